// Round 1
// baseline (1745.012 us; speedup 1.0000x reference)
//
#include <hip/hip_runtime.h>
#include <hip/hip_bf16.h>

#define D_IN  500
#define BATCH 131072
#define BM    64

typedef unsigned short u16;
typedef unsigned int   u32;
using f32x4  = __attribute__((ext_vector_type(4))) float;
using bf16x8 = __attribute__((ext_vector_type(8))) short;

__device__ __forceinline__ u16 f2bf(float f) {
  u32 b = __builtin_bit_cast(u32, f);
  b += 0x7FFFu + ((b >> 16) & 1u);
  return (u16)(b >> 16);
}
__device__ __forceinline__ float bf2f(u32 hbits) {
  return __builtin_bit_cast(float, hbits << 16);
}

// XLA/Eigen fast-tanh f32 (clamped rational) — matches jnp.tanh on XLA backends.
__device__ __forceinline__ float xla_tanh(float z) {
  float xc = fminf(fmaxf(z, -7.90531110764903f), 7.90531110764903f);
  float x2 = xc * xc;
  float p = fmaf(x2, -2.76076847742355e-16f, 2.00018790482477e-13f);
  p = fmaf(x2, p, -8.60467152213735e-11f);
  p = fmaf(x2, p,  5.12229709037114e-08f);
  p = fmaf(x2, p,  1.48572235717979e-05f);
  p = fmaf(x2, p,  6.37261928875436e-04f);
  p = fmaf(x2, p,  4.89352455891786e-03f);
  p = xc * p;
  float q = fmaf(x2, 1.19825839466702e-06f, 1.18534705686654e-04f);
  q = fmaf(x2, q, 2.26843463243900e-03f);
  q = fmaf(x2, q, 4.89352518554385e-03f);
  return (fabsf(z) < 0.0004f) ? z : (p / q);
}

// ---------------------------------------------------------------------------
// prep: build extended bf16 B-matrix (Omega^T | one-hots | beta | alpha | ones)
// directly in MFMA A-fragment order.  544 frag-blocks of 1 KB in ws.
// Chunks 0..3: n in [0,512), frag-block = (seg*16 + ks*4 + rf), seg = chunk*8+nw*4+jg.
// Chunk 4 (extras, 32 wide): frag-block = 512 + (nw*4+jg)*4 + ks.
// Element: value = W[j][n]; lane supplies n = base + (lane&15), j = kbase + (lane>>4)*8 + e.
// ---------------------------------------------------------------------------
__global__ void disc_prep(const float* __restrict__ Omega,
                          const float* __restrict__ alpha,
                          const float* __restrict__ beta,
                          const int* __restrict__ sector_id,
                          const int* __restrict__ mq_id,
                          u16* __restrict__ wsA,
                          float* __restrict__ l_all) {
  int idx = blockIdx.x * 256 + threadIdx.x;   // over 544*512 = 278528 elements
  if (idx == 0) *l_all = 0.0f;
  if (idx >= 544 * 512) return;
  int blk    = idx >> 9;
  int within = idx & 511;
  int lane   = within >> 3;
  int e      = within & 7;
  int n, j;
  if (blk < 512) {
    int seg = blk >> 4;
    int f   = blk & 15;
    int chunk = seg >> 3;
    int nw    = (seg >> 2) & 1;
    int jg    = seg & 3;
    int ks = f >> 2, rf = f & 3;
    n = chunk * 128 + nw * 64 + rf * 16 + (lane & 15);
    j = jg * 128 + ks * 32 + ((lane >> 4) << 3) + e;
  } else {
    int b4  = blk - 512;
    int sub = b4 >> 2;
    int ks  = b4 & 3;
    int nw = sub >> 2, jg = sub & 3;
    n = 512 + nw * 16 + (lane & 15);
    j = jg * 128 + ks * 32 + ((lane >> 4) << 3) + e;
  }
  float v = 0.0f;
  if (j < D_IN) {
    if (n < D_IN)       v = Omega[j * D_IN + n];
    else if (n < 512)   v = 0.0f;                                  // K/N pad
    else if (n < 523)   v = (sector_id[j] == (n - 512)) ? 1.0f : 0.0f;
    else if (n < 533)   v = (mq_id[j]     == (n - 523)) ? 1.0f : 0.0f;
    else if (n == 533)  v = beta[j];
    else if (n == 534)  v = alpha[j];
    else if (n == 535)  v = 1.0f;                                  // ones -> sum(d)
  }
  wsA[idx] = f2bf(v);
}

// ---------------------------------------------------------------------------
// main: per 64-row block:
//  phase1: stage d = x - x_bw as bf16 into swizzled LDS (row-major [64][512])
//  phase2: exact fp32 cheap terms (sum|d|, nnz, sum x_bw) from L2-hot x
//  GEMM:   C'[n,i] = sum_j Omega^T[n,j] * d^T[j,i] via mfma_f32_16x16x32_bf16,
//          8 waves = 2 n-halves x 4 K-slices, 64x64 tile/wave, no barriers.
//          Epilogue per chunk: pdqd += C'[n,i] * d[i,n] (b64 LDS reads).
//          Extras chunk -> LDS atomicAdd partials (relu applied after full K).
// ---------------------------------------------------------------------------
__global__ __launch_bounds__(512, 4) void disc_main(
    const float* __restrict__ x, const float* __restrict__ x_bw,
    const u16* __restrict__ wsA,
    float* __restrict__ tot_out, float* __restrict__ l_all) {
  __shared__ alignas(16) u16 ldsA[BM * 512];  // 64 KB, swizzled: byte ^= (row&7)<<4
  __shared__ float s_ext[BM][24];
  __shared__ float s_dqd[BM][8];
  __shared__ float s_sabs[BM];
  __shared__ float s_nnz[BM];
  __shared__ float s_sxbw;

  const int t = threadIdx.x;
  const float* xblk = x + (size_t)blockIdx.x * (BM * D_IN);

  // zero extras partials
  for (int z = t; z < BM * 24; z += 512) ((float*)s_ext)[z] = 0.0f;

  // zero-pad d columns 500..511
  for (int z = t; z < BM * 12; z += 512) {
    int r = z / 12, c = 500 + (z - r * 12);
    int byte = ((r << 10) + (c << 1)) ^ ((r & 7) << 4);
    *(u16*)((char*)ldsA + byte) = 0;
  }

  // phase 1: coalesced float4 slab load -> bf16 d into LDS
  for (int v4 = t; v4 < (BM * D_IN) / 4; v4 += 512) {   // 8000 float4s
    int f = v4 << 2;
    int r = f / D_IN;
    int c = f - r * D_IN;          // multiple of 4 (500 % 4 == 0, no row crossing)
    float4 xv = *(const float4*)(xblk + f);
    float4 bw = *(const float4*)(x_bw + c);
    u32 lo = (u32)f2bf(xv.x - bw.x) | ((u32)f2bf(xv.y - bw.y) << 16);
    u32 hi = (u32)f2bf(xv.z - bw.z) | ((u32)f2bf(xv.w - bw.w) << 16);
    int byte = ((r << 10) + (c << 1)) ^ ((r & 7) << 4);
    *(uint2*)((char*)ldsA + byte) = make_uint2(lo, hi);
  }

  // phase 2: exact fp32 cheap terms (x slab is L2-hot)
  {
    int r = t >> 3, s = t & 7;
    const float* xr = xblk + r * D_IN;
    float sabs = 0.f, nnz = 0.f, sxbw = 0.f;
    for (int c = s; c < D_IN; c += 8) {
      float xv = xr[c], bw = x_bw[c];
      sabs += fabsf(xv - bw);
      nnz  += (xv > 0.001f) ? 1.0f : 0.0f;
      sxbw += bw;
    }
    #pragma unroll
    for (int m = 1; m < 8; m <<= 1) {
      sabs += __shfl_xor(sabs, m, 64);
      nnz  += __shfl_xor(nnz,  m, 64);
      sxbw += __shfl_xor(sxbw, m, 64);
    }
    if (s == 0) { s_sabs[r] = sabs; s_nnz[r] = nnz; }
    if (t == 0) s_sxbw = sxbw;
  }

  __syncthreads();

  // ---- GEMM phase (barrier-free) ----
  const int l   = t & 63;
  const int w   = t >> 6;
  const int nw  = w >> 2;     // n-half
  const int jg  = w & 3;      // K-slice
  const int l15 = l & 15;
  const int l4  = l >> 4;
  const f32x4 fzero = {0.f, 0.f, 0.f, 0.f};

  float pdqd[4] = {0.f, 0.f, 0.f, 0.f};

  #pragma unroll
  for (int chunk = 0; chunk < 4; ++chunk) {
    const int seg = chunk * 8 + nw * 4 + jg;
    f32x4 acc[4][4];
    #pragma unroll
    for (int rf = 0; rf < 4; ++rf)
      #pragma unroll
      for (int cf = 0; cf < 4; ++cf) acc[rf][cf] = fzero;

    #pragma unroll
    for (int ks = 0; ks < 4; ++ks) {
      const int kk = jg * 128 + ks * 32 + l4 * 8;
      bf16x8 bfrag[4];
      #pragma unroll
      for (int cf = 0; cf < 4; ++cf) {
        int i = cf * 16 + l15;
        int byte = ((i << 10) + (kk << 1)) ^ ((i & 7) << 4);
        bfrag[cf] = *(const bf16x8*)((const char*)ldsA + byte);
      }
      #pragma unroll
      for (int rf = 0; rf < 4; ++rf) {
        bf16x8 afrag = *(const bf16x8*)(wsA + ((seg * 16 + ks * 4 + rf) << 9) + (l << 3));
        #pragma unroll
        for (int cf = 0; cf < 4; ++cf)
          acc[rf][cf] = __builtin_amdgcn_mfma_f32_16x16x32_bf16(afrag, bfrag[cf], acc[rf][cf], 0, 0, 0);
      }
    }
    // dQd epilogue: C'[n,i] * d[i,n], rows n = nbase..nbase+3 contiguous -> b64
    #pragma unroll
    for (int rf = 0; rf < 4; ++rf) {
      const int nbase = chunk * 128 + nw * 64 + rf * 16 + l4 * 4;
      #pragma unroll
      for (int cf = 0; cf < 4; ++cf) {
        int i = cf * 16 + l15;
        int byte = ((i << 10) + (nbase << 1)) ^ ((i & 7) << 4);
        uint2 dv = *(const uint2*)((const char*)ldsA + byte);
        pdqd[cf] += acc[rf][cf][0] * bf2f(dv.x & 0xFFFFu)
                  + acc[rf][cf][1] * bf2f(dv.x >> 16)
                  + acc[rf][cf][2] * bf2f(dv.y & 0xFFFFu)
                  + acc[rf][cf][3] * bf2f(dv.y >> 16);
      }
    }
  }

  // extras chunk (32 n-cols: sector, mq, beta, alpha, ones)
  {
    const int sub = nw * 4 + jg;
    f32x4 acc4[4];
    #pragma unroll
    for (int cf = 0; cf < 4; ++cf) acc4[cf] = fzero;
    #pragma unroll
    for (int ks = 0; ks < 4; ++ks) {
      const int kk = jg * 128 + ks * 32 + l4 * 8;
      bf16x8 afrag = *(const bf16x8*)(wsA + ((512 + sub * 4 + ks) << 9) + (l << 3));
      #pragma unroll
      for (int cf = 0; cf < 4; ++cf) {
        int i = cf * 16 + l15;
        int byte = ((i << 10) + (kk << 1)) ^ ((i & 7) << 4);
        bf16x8 bfrag = *(const bf16x8*)((const char*)ldsA + byte);
        acc4[cf] = __builtin_amdgcn_mfma_f32_16x16x32_bf16(afrag, bfrag, acc4[cf], 0, 0, 0);
      }
    }
    #pragma unroll
    for (int cf = 0; cf < 4; ++cf) {
      int i = cf * 16 + l15;
      #pragma unroll
      for (int q = 0; q < 4; ++q) {
        int n = 512 + nw * 16 + l4 * 4 + q;
        if (n < 536) atomicAdd(&s_ext[i][n - 512], acc4[cf][q]);
      }
    }
  }

  // reduce pdqd across the 4 lane-groups holding the same i
  #pragma unroll
  for (int cf = 0; cf < 4; ++cf) {
    float v = pdqd[cf];
    v += __shfl_xor(v, 16, 64);
    v += __shfl_xor(v, 32, 64);
    if (l < 16) s_dqd[cf * 16 + l][w] = v;
  }
  __syncthreads();

  // per-row assembly
  if (t < BM) {
    float dqd = 0.f;
    #pragma unroll
    for (int ww = 0; ww < 8; ++ww) dqd += s_dqd[t][ww];
    float tex = 0.f;
    #pragma unroll
    for (int c = 0; c < 22; ++c)                 // sector(11) + mq(10) + beta(1)
      tex += fmaxf(fabsf(s_ext[t][c]) - 0.1f, 0.f);
    float l2 = s_ext[t][22];                     // d @ alpha
    float sx = s_ext[t][23] + s_sxbw;            // sum(d) + sum(x_bw) = sum(x)
    float sabs = s_sabs[t], nnz = s_nnz[t];
    float tot = tex
      + fmaxf(1.f - sx, 0.f) + fmaxf(sx - 1.f, 0.f)
      + fmaxf(sabs - 0.05f, 0.f)
      + fmaxf(nnz - 70.f, 0.f) + fmaxf(69.f - nnz, 0.f)
      + fmaxf(dqd - 0.01f, 0.f) + fmaxf(0.0025f - dqd, 0.f)
      + fmaxf(100.f * dqd - 100.f * l2 - 1000.f, 0.f);
    tot_out[(size_t)blockIdx.x * BM + t] = tot;
    float bs = sabs;
    #pragma unroll
    for (int m = 1; m < 64; m <<= 1) bs += __shfl_xor(bs, m, 64);
    if (t == 0) atomicAdd(l_all, bs);
  }
}

// ---------------------------------------------------------------------------
__global__ void disc_final(const float* __restrict__ tot_in,
                           const float* __restrict__ l_all,
                           float* __restrict__ out) {
  int i = blockIdx.x * 256 + threadIdx.x;
  if (i >= BATCH) return;
  float lterm = fmaxf(0.6f - 0.5f * (*l_all), 0.0f);
  float z = (tot_in[i] + lterm) * 0.01f;
  out[i] = fmaxf(1.0f - xla_tanh(z), 0.0f);
}

extern "C" void kernel_launch(void* const* d_in, const int* in_sizes, int n_in,
                              void* d_out, int out_size, void* d_ws, size_t ws_size,
                              hipStream_t stream) {
  const float* x     = (const float*)d_in[0];
  const float* x_bw  = (const float*)d_in[1];
  const float* alpha = (const float*)d_in[2];
  const float* beta  = (const float*)d_in[3];
  const float* Omega = (const float*)d_in[4];
  const int* sector_id = (const int*)d_in[5];
  const int* mq_id     = (const int*)d_in[6];
  float* out = (float*)d_out;

  char* ws = (char*)d_ws;
  u16*   wsA   = (u16*)ws;                          // 544 KB fragment stream
  float* l_all = (float*)(ws + 544 * 1024);         // 4 B global |d| accumulator
  float* tot   = (float*)(ws + 544 * 1024 + 1024);  // 512 KB per-row tot (sans l_all term)

  disc_prep<<<1088, 256, 0, stream>>>(Omega, alpha, beta, sector_id, mq_id, wsA, l_all);
  disc_main<<<BATCH / BM, 512, 0, stream>>>(x, x_bw, wsA, tot, l_all);
  disc_final<<<BATCH / 256, 256, 0, stream>>>(tot, l_all, out);
}

// Round 2
// 541.094 us; speedup vs baseline: 3.2250x; 3.2250x over previous
//
#include <hip/hip_runtime.h>
#include <hip/hip_bf16.h>

#define D_IN  500
#define BATCH 131072
#define BM    64

typedef unsigned short u16;
typedef unsigned int   u32;
using f32x4  = __attribute__((ext_vector_type(4))) float;
using bf16x8 = __attribute__((ext_vector_type(8))) short;

__device__ __forceinline__ u16 f2bf(float f) {
  u32 b = __builtin_bit_cast(u32, f);
  b += 0x7FFFu + ((b >> 16) & 1u);
  return (u16)(b >> 16);
}
__device__ __forceinline__ float bf2f(u32 hbits) {
  return __builtin_bit_cast(float, hbits << 16);
}

// XLA/Eigen fast-tanh f32 (clamped rational) — matches jnp.tanh on XLA backends.
__device__ __forceinline__ float xla_tanh(float z) {
  float xc = fminf(fmaxf(z, -7.90531110764903f), 7.90531110764903f);
  float x2 = xc * xc;
  float p = fmaf(x2, -2.76076847742355e-16f, 2.00018790482477e-13f);
  p = fmaf(x2, p, -8.60467152213735e-11f);
  p = fmaf(x2, p,  5.12229709037114e-08f);
  p = fmaf(x2, p,  1.48572235717979e-05f);
  p = fmaf(x2, p,  6.37261928875436e-04f);
  p = fmaf(x2, p,  4.89352455891786e-03f);
  p = xc * p;
  float q = fmaf(x2, 1.19825839466702e-06f, 1.18534705686654e-04f);
  q = fmaf(x2, q, 2.26843463243900e-03f);
  q = fmaf(x2, q, 4.89352518554385e-03f);
  return (fabsf(z) < 0.0004f) ? z : (p / q);
}

// ---------------------------------------------------------------------------
// prep: build extended bf16 B-matrix (Omega^T | one-hots | beta | alpha | ones)
// in MFMA A-fragment order. 544 frag-blocks of 1 KB in ws.
// Main blocks (blk<512): id = chunk*32 + nw*16 + jg*4 + ks
//   n = chunk*32 + nw*16 + (lane&15);  j = jg*128 + ks*32 + (lane>>4)*8 + e
// Extras (blk>=512): id = 512 + (nw*4+jg)*4 + ks
//   n = 512 + nw*16 + (lane&15);       j = jg*128 + ks*32 + (lane>>4)*8 + e
// ---------------------------------------------------------------------------
__global__ void disc_prep(const float* __restrict__ Omega,
                          const float* __restrict__ alpha,
                          const float* __restrict__ beta,
                          const int* __restrict__ sector_id,
                          const int* __restrict__ mq_id,
                          u16* __restrict__ wsA,
                          float* __restrict__ l_all) {
  int idx = blockIdx.x * 256 + threadIdx.x;   // over 544*512 = 278528 elements
  if (idx == 0) *l_all = 0.0f;
  if (idx >= 544 * 512) return;
  int blk    = idx >> 9;
  int within = idx & 511;
  int lane   = within >> 3;
  int e      = within & 7;
  int n, j;
  if (blk < 512) {
    int chunk = blk >> 5;
    int nw    = (blk >> 4) & 1;
    int jg    = (blk >> 2) & 3;
    int ks    = blk & 3;
    n = chunk * 32 + nw * 16 + (lane & 15);
    j = jg * 128 + ks * 32 + ((lane >> 4) << 3) + e;
  } else {
    int b4  = blk - 512;
    int sub = b4 >> 2;
    int ks  = b4 & 3;
    int nw = sub >> 2, jg = sub & 3;
    n = 512 + nw * 16 + (lane & 15);
    j = jg * 128 + ks * 32 + ((lane >> 4) << 3) + e;
  }
  float v = 0.0f;
  if (j < D_IN) {
    if (n < D_IN)       v = Omega[j * D_IN + n];
    else if (n < 512)   v = 0.0f;                                  // N pad
    else if (n < 523)   v = (sector_id[j] == (n - 512)) ? 1.0f : 0.0f;
    else if (n < 533)   v = (mq_id[j]     == (n - 523)) ? 1.0f : 0.0f;
    else if (n == 533)  v = beta[j];
    else if (n == 534)  v = alpha[j];
    else if (n == 535)  v = 1.0f;                                  // ones -> sum(d)
  }
  wsA[idx] = f2bf(v);
}

// ---------------------------------------------------------------------------
// main: per 64-row block:
//  phase1: stage d = x - x_bw as bf16 into swizzled LDS (row-major [64][512])
//  phase2: exact fp32 cheap terms (sum|d|, nnz, sum x_bw) from L2-hot x
//  GEMM:   C'[n,i] = sum_j W[j,n] * d[i,j] via mfma_f32_16x16x32_bf16.
//          8 waves = 2 n-halves (nw) x 4 K-slices (jg); per wave: hold the
//          entire d^T K-slice in registers (bfs[4][4], 64 VGPR, read from LDS
//          ONCE), then 16 rolled n-chunks of {4 global A-frag loads, 16 MFMA,
//          dQd epilogue}. Extras reuse bfs -> zero extra LDS traffic.
// ---------------------------------------------------------------------------
__global__ __launch_bounds__(512, 2) void disc_main(
    const float* __restrict__ x, const float* __restrict__ x_bw,
    const u16* __restrict__ wsA,
    float* __restrict__ tot_out, float* __restrict__ l_all) {
  __shared__ alignas(16) u16 ldsA[BM * 512];  // 64 KB, swizzled: byte ^= (row&7)<<4
  __shared__ float s_ext[BM][25];             // stride 25: conflict-free atomics
  __shared__ float s_dqd[BM][8];
  __shared__ float s_sabs[BM];
  __shared__ float s_nnz[BM];
  __shared__ float s_sxbw;

  const int t = threadIdx.x;
  const float* xblk = x + (size_t)blockIdx.x * (BM * D_IN);

  // zero extras partials
  for (int z = t; z < BM * 25; z += 512) ((float*)s_ext)[z] = 0.0f;

  // zero-pad d columns 500..511
  for (int z = t; z < BM * 12; z += 512) {
    int r = z / 12, c = 500 + (z - r * 12);
    int byte = ((r << 10) + (c << 1)) ^ ((r & 7) << 4);
    *(u16*)((char*)ldsA + byte) = 0;
  }

  // phase 1: coalesced float4 slab load -> bf16 d into LDS
  for (int v4 = t; v4 < (BM * D_IN) / 4; v4 += 512) {   // 8000 float4s
    int f = v4 << 2;
    int r = f / D_IN;
    int c = f - r * D_IN;          // multiple of 4 (500 % 4 == 0, no row crossing)
    float4 xv = *(const float4*)(xblk + f);
    float4 bw = *(const float4*)(x_bw + c);
    u32 lo = (u32)f2bf(xv.x - bw.x) | ((u32)f2bf(xv.y - bw.y) << 16);
    u32 hi = (u32)f2bf(xv.z - bw.z) | ((u32)f2bf(xv.w - bw.w) << 16);
    int byte = ((r << 10) + (c << 1)) ^ ((r & 7) << 4);
    *(uint2*)((char*)ldsA + byte) = make_uint2(lo, hi);
  }

  // phase 2: exact fp32 cheap terms (x slab is L2-hot)
  {
    int r = t >> 3, s = t & 7;
    const float* xr = xblk + r * D_IN;
    float sabs = 0.f, nnz = 0.f, sxbw = 0.f;
    for (int c = s; c < D_IN; c += 8) {
      float xv = xr[c], bw = x_bw[c];
      sabs += fabsf(xv - bw);
      nnz  += (xv > 0.001f) ? 1.0f : 0.0f;
      sxbw += bw;
    }
    #pragma unroll
    for (int m = 1; m < 8; m <<= 1) {
      sabs += __shfl_xor(sabs, m, 64);
      nnz  += __shfl_xor(nnz,  m, 64);
      sxbw += __shfl_xor(sxbw, m, 64);
    }
    if (s == 0) { s_sabs[r] = sabs; s_nnz[r] = nnz; }
    if (t == 0) s_sxbw = sxbw;
  }

  __syncthreads();

  // ---- GEMM phase (barrier-free) ----
  const int l   = t & 63;
  const int w   = t >> 6;
  const int nw  = w >> 2;     // n-half within 32-col chunk
  const int jg  = w & 3;      // K-slice (128 wide)
  const int l15 = l & 15;
  const int l4  = l >> 4;
  const f32x4 fzero = {0.f, 0.f, 0.f, 0.f};

  // preload the wave's entire d^T K-slice: bfs[ks][cf] covers
  // j in [jg*128+ks*32+l4*8, +8), i = cf*16+l15.   (64 VGPRs, pinned)
  bf16x8 bfs[4][4];
  #pragma unroll
  for (int ks = 0; ks < 4; ++ks) {
    const int kk = jg * 128 + ks * 32 + l4 * 8;
    #pragma unroll
    for (int cf = 0; cf < 4; ++cf) {
      int i = cf * 16 + l15;
      int byte = ((i << 10) + (kk << 1)) ^ ((i & 7) << 4);
      bfs[ks][cf] = *(const bf16x8*)((const char*)ldsA + byte);
    }
  }

  float pdqd[4] = {0.f, 0.f, 0.f, 0.f};
  const u16* wA = wsA + (((nw * 16 + jg * 4) << 9)) + (l << 3);

  #pragma unroll 1
  for (int chunk = 0; chunk < 16; ++chunk) {
    bf16x8 af[4];
    #pragma unroll
    for (int ks = 0; ks < 4; ++ks)
      af[ks] = *(const bf16x8*)(wA + (((chunk * 32 + ks) << 9)));
    f32x4 acc[4] = {fzero, fzero, fzero, fzero};
    #pragma unroll
    for (int ks = 0; ks < 4; ++ks)
      #pragma unroll
      for (int cf = 0; cf < 4; ++cf)
        acc[cf] = __builtin_amdgcn_mfma_f32_16x16x32_bf16(af[ks], bfs[ks][cf], acc[cf], 0, 0, 0);
    // dQd epilogue: C'[n,i] * d[i,n]; n = nbase..nbase+3 contiguous -> b64 read
    const int nbase = chunk * 32 + nw * 16 + l4 * 4;
    #pragma unroll
    for (int cf = 0; cf < 4; ++cf) {
      int i = cf * 16 + l15;
      int byte = ((i << 10) + (nbase << 1)) ^ ((i & 7) << 4);
      uint2 dv = *(const uint2*)((const char*)ldsA + byte);
      pdqd[cf] += acc[cf][0] * bf2f(dv.x & 0xFFFFu)
                + acc[cf][1] * bf2f(dv.x >> 16)
                + acc[cf][2] * bf2f(dv.y & 0xFFFFu)
                + acc[cf][3] * bf2f(dv.y >> 16);
    }
  }

  // extras chunk (32 n-cols: sector, mq, beta, alpha, ones) — reuses bfs
  {
    const int sub = nw * 4 + jg;
    f32x4 acc4[4];
    #pragma unroll
    for (int cf = 0; cf < 4; ++cf) acc4[cf] = fzero;
    #pragma unroll
    for (int ks = 0; ks < 4; ++ks) {
      bf16x8 afrag = *(const bf16x8*)(wsA + ((512 + sub * 4 + ks) << 9) + (l << 3));
      #pragma unroll
      for (int cf = 0; cf < 4; ++cf)
        acc4[cf] = __builtin_amdgcn_mfma_f32_16x16x32_bf16(afrag, bfs[ks][cf], acc4[cf], 0, 0, 0);
    }
    #pragma unroll
    for (int cf = 0; cf < 4; ++cf) {
      int i = cf * 16 + l15;
      #pragma unroll
      for (int q = 0; q < 4; ++q) {
        int n = 512 + nw * 16 + l4 * 4 + q;
        if (n < 536) atomicAdd(&s_ext[i][n - 512], acc4[cf][q]);
      }
    }
  }

  // reduce pdqd across the 4 lane-groups holding the same i
  #pragma unroll
  for (int cf = 0; cf < 4; ++cf) {
    float v = pdqd[cf];
    v += __shfl_xor(v, 16, 64);
    v += __shfl_xor(v, 32, 64);
    if (l < 16) s_dqd[cf * 16 + l][w] = v;
  }
  __syncthreads();

  // per-row assembly
  if (t < BM) {
    float dqd = 0.f;
    #pragma unroll
    for (int ww = 0; ww < 8; ++ww) dqd += s_dqd[t][ww];
    float tex = 0.f;
    #pragma unroll
    for (int c = 0; c < 22; ++c)                 // sector(11) + mq(10) + beta(1)
      tex += fmaxf(fabsf(s_ext[t][c]) - 0.1f, 0.f);
    float l2 = s_ext[t][22];                     // d @ alpha
    float sx = s_ext[t][23] + s_sxbw;            // sum(d) + sum(x_bw) = sum(x)
    float sabs = s_sabs[t], nnz = s_nnz[t];
    float tot = tex
      + fmaxf(1.f - sx, 0.f) + fmaxf(sx - 1.f, 0.f)
      + fmaxf(sabs - 0.05f, 0.f)
      + fmaxf(nnz - 70.f, 0.f) + fmaxf(69.f - nnz, 0.f)
      + fmaxf(dqd - 0.01f, 0.f) + fmaxf(0.0025f - dqd, 0.f)
      + fmaxf(100.f * dqd - 100.f * l2 - 1000.f, 0.f);
    tot_out[(size_t)blockIdx.x * BM + t] = tot;
    float bs = sabs;
    #pragma unroll
    for (int m = 1; m < 64; m <<= 1) bs += __shfl_xor(bs, m, 64);
    if (t == 0) atomicAdd(l_all, bs);
  }
}

// ---------------------------------------------------------------------------
__global__ void disc_final(const float* __restrict__ tot_in,
                           const float* __restrict__ l_all,
                           float* __restrict__ out) {
  int i = blockIdx.x * 256 + threadIdx.x;
  if (i >= BATCH) return;
  float lterm = fmaxf(0.6f - 0.5f * (*l_all), 0.0f);
  float z = (tot_in[i] + lterm) * 0.01f;
  out[i] = fmaxf(1.0f - xla_tanh(z), 0.0f);
}

extern "C" void kernel_launch(void* const* d_in, const int* in_sizes, int n_in,
                              void* d_out, int out_size, void* d_ws, size_t ws_size,
                              hipStream_t stream) {
  const float* x     = (const float*)d_in[0];
  const float* x_bw  = (const float*)d_in[1];
  const float* alpha = (const float*)d_in[2];
  const float* beta  = (const float*)d_in[3];
  const float* Omega = (const float*)d_in[4];
  const int* sector_id = (const int*)d_in[5];
  const int* mq_id     = (const int*)d_in[6];
  float* out = (float*)d_out;

  char* ws = (char*)d_ws;
  u16*   wsA   = (u16*)ws;                          // 544 KB fragment stream
  float* l_all = (float*)(ws + 544 * 1024);         // 4 B global |d| accumulator
  float* tot   = (float*)(ws + 544 * 1024 + 1024);  // 512 KB per-row tot (sans l_all term)

  disc_prep<<<1088, 256, 0, stream>>>(Omega, alpha, beta, sector_id, mq_id, wsA, l_all);
  disc_main<<<BATCH / BM, 512, 0, stream>>>(x, x_bw, wsA, tot, l_all);
  disc_final<<<BATCH / 256, 256, 0, stream>>>(tot, l_all, out);
}